// Round 12
// baseline (3858.014 us; speedup 1.0000x reference)
//
#include <hip/hip_runtime.h>

// Decoder: emb -> 3-layer GRU -> scaled-dot attention over encoder -> tanh(linear) -> logits
// Round 11: WRITE-ONCE ring (full trajectory, no slot reuse) -> consumers use CACHED loads.
//   r10 tell: residency attempts dead (VGPR pinned at 128, dur flat). Residual cost model:
//   every published 32KB h-block is re-read by 32 WGs via sc0-sc1 BYPASS loads (never
//   L2-cacheable) -> ~12MB/phase of IC broadcast. Write-once ring makes cached reads safe
//   (each address written exactly once per launch; launch-boundary acquire covers replays),
//   same-XCD readers share in L2, and the WAR/above-poll is deleted (layers decouple).
//   Capacity: L0/L1 rings live in d_out's out_attn region (dead until scores GEMM),
//   L2 ring in the XA slot (dead until context GEMM), h[-1] slots in old ring area.

typedef unsigned short u16;
typedef __attribute__((ext_vector_type(8))) __bf16 bf16x8;
typedef __attribute__((ext_vector_type(4))) float f32x4;
typedef __attribute__((ext_vector_type(4))) unsigned int u32x4;

#define D_ 512
#define S_ 512
#define SE_ 512
#define B_ 128
#define V_ 100

__device__ __forceinline__ float bf2f(u16 v) {
  unsigned u = ((unsigned)v) << 16;
  return __builtin_bit_cast(float, u);
}
__device__ __forceinline__ u16 f2bf(float f) {
  unsigned u = __builtin_bit_cast(unsigned, f);
  u += 0x7FFF + ((u >> 16) & 1);   // RNE
  return (u16)(u >> 16);
}

// ---------------- elementwise converts ----------------
__global__ __launch_bounds__(256) void cvt_f32_bf16(const float* __restrict__ src,
                                                    u16* __restrict__ dst, long n4) {
  long i = (long)blockIdx.x * 256 + threadIdx.x;
  long stride = (long)gridDim.x * 256;
  for (; i < n4; i += stride) {
    float4 v = ((const float4*)src)[i];
    unsigned long long p = (unsigned long long)f2bf(v.x) |
                           ((unsigned long long)f2bf(v.y) << 16) |
                           ((unsigned long long)f2bf(v.z) << 32) |
                           ((unsigned long long)f2bf(v.w) << 48);
    ((unsigned long long*)dst)[i] = p;
  }
}

__global__ __launch_bounds__(256) void zero_flags(unsigned* __restrict__ f, int n) {
  int i = blockIdx.x * 256 + threadIdx.x;
  if (i < n)
    __hip_atomic_store(&f[i], 0u, __ATOMIC_RELAXED, __HIP_MEMORY_SCOPE_AGENT);
}

// enc (B,SE,D) f32 -> encT (B,D,SE) bf16
__global__ __launch_bounds__(256) void transpose_enc(const float* __restrict__ enc,
                                                     u16* __restrict__ encT) {
  __shared__ u16 tile[64][72];
  int b = blockIdx.z, d0 = blockIdx.x * 64, se0 = blockIdx.y * 64;
  const float* src = enc + (long)b * SE_ * D_;
  int t = threadIdx.x;
  int r = t >> 2, cq = (t & 3) * 16;
#pragma unroll
  for (int j = 0; j < 4; ++j) {
    float4 v = *(const float4*)(src + (long)(se0 + r) * D_ + d0 + cq + j * 4);
    tile[r][cq + j * 4 + 0] = f2bf(v.x);
    tile[r][cq + j * 4 + 1] = f2bf(v.y);
    tile[r][cq + j * 4 + 2] = f2bf(v.z);
    tile[r][cq + j * 4 + 3] = f2bf(v.w);
  }
  __syncthreads();
  u16* dst = encT + (long)b * D_ * SE_;
  u16 ov[16];
#pragma unroll
  for (int j = 0; j < 16; ++j) ov[j] = tile[cq + j][r];
  *(u32x4*)(dst + (long)(d0 + r) * SE_ + se0 + cq) = *(u32x4*)&ov[0];
  *(u32x4*)(dst + (long)(d0 + r) * SE_ + se0 + cq + 8) = *(u32x4*)&ov[8];
}

// in-place fp32 softmax over 512-wide rows + bf16 copy
__global__ __launch_bounds__(256) void softmax_rows(float* __restrict__ sc,
                                                    u16* __restrict__ abf) {
  long row = (long)blockIdx.x * 4 + (threadIdx.x >> 6);
  int lane = threadIdx.x & 63;
  float* p = sc + row * 512;
  float4 v0 = ((const float4*)p)[lane * 2];
  float4 v1 = ((const float4*)p)[lane * 2 + 1];
  float vals[8] = {v0.x, v0.y, v0.z, v0.w, v1.x, v1.y, v1.z, v1.w};
  float m = vals[0];
#pragma unroll
  for (int j = 1; j < 8; ++j) m = fmaxf(m, vals[j]);
#pragma unroll
  for (int o = 32; o; o >>= 1) m = fmaxf(m, __shfl_xor(m, o, 64));
  float s = 0.f;
#pragma unroll
  for (int j = 0; j < 8; ++j) { vals[j] = __expf(vals[j] - m); s += vals[j]; }
#pragma unroll
  for (int o = 32; o; o >>= 1) s += __shfl_xor(s, o, 64);
  float inv = 1.f / s;
  u16 ob[8];
#pragma unroll
  for (int j = 0; j < 8; ++j) { vals[j] *= inv; ob[j] = f2bf(vals[j]); }
  float4 w0 = {vals[0], vals[1], vals[2], vals[3]};
  float4 w1 = {vals[4], vals[5], vals[6], vals[7]};
  ((float4*)p)[lane * 2] = w0;
  ((float4*)p)[lane * 2 + 1] = w1;
  *(u32x4*)(abf + row * 512 + lane * 8) = *(u32x4*)ob;
}

// ---------------- generic C = A(M,K) @ W(N,K)^T, bf16 in / f32 acc ----------------
template <int MODE, int WF32>
__global__ __launch_bounds__(256) void gemm_xwt(
    const u16* __restrict__ A1, const u16* __restrict__ A2, const u16* __restrict__ W,
    const float* __restrict__ bias, void* __restrict__ Cout, const u16* __restrict__ maskSrc,
    int N, int K, int K1, long sAb, long sWb, long sCb, float scale, int ldc) {
  __shared__ u16 sA[128][32];
  __shared__ u16 sW_[128][32];
  int bz = blockIdx.z;
  int n0 = blockIdx.x * 128, m0 = blockIdx.y * 128;
  const u16* Ab = A1 + (long)bz * sAb;
  int t = threadIdx.x, wave = t >> 6, lane = t & 63;
  int wm = (wave >> 1) * 64, wn = (wave & 1) * 64;
  f32x4 acc[4][4] = {};
  for (int kk = 0; kk < K; kk += 32) {
#pragma unroll
    for (int i = 0; i < 2; ++i) {
      int id = t + i * 256;
      int row = id >> 2, c8 = (id & 3) * 8;
      const u16* src;
      if (MODE == 3 && kk >= K1)
        src = A2 + (long)(m0 + row) * (K - K1) + (kk - K1) + c8;
      else
        src = Ab + (long)(m0 + row) * K1 + kk + c8;
      *(u32x4*)&sA[row][c8] = *(const u32x4*)src;
    }
#pragma unroll
    for (int i = 0; i < 2; ++i) {
      int id = t + i * 256;
      int row = id >> 2, c8 = (id & 3) * 8;
      if (WF32) {
        const float* wsrc = ((const float*)W) + (long)bz * sWb + (long)(n0 + row) * K + kk + c8;
        float4 va = *(const float4*)wsrc;
        float4 vb = *(const float4*)(wsrc + 4);
        u16 tmp[8] = {f2bf(va.x), f2bf(va.y), f2bf(va.z), f2bf(va.w),
                      f2bf(vb.x), f2bf(vb.y), f2bf(vb.z), f2bf(vb.w)};
        *(u32x4*)&sW_[row][c8] = *(u32x4*)tmp;
      } else {
        u32x4 v = {0u, 0u, 0u, 0u};
        if (n0 + row < N) v = *(const u32x4*)(W + (long)bz * sWb + (long)(n0 + row) * K + kk + c8);
        *(u32x4*)&sW_[row][c8] = v;
      }
    }
    __syncthreads();
    int k8 = (lane >> 4) * 8, rr = lane & 15;
    bf16x8 wf[4];
#pragma unroll
    for (int nt = 0; nt < 4; ++nt)
      wf[nt] = __builtin_bit_cast(bf16x8, *(const u32x4*)&sW_[wn + nt * 16 + rr][k8]);
#pragma unroll
    for (int mt = 0; mt < 4; ++mt) {
      bf16x8 af = __builtin_bit_cast(bf16x8, *(const u32x4*)&sA[wm + mt * 16 + rr][k8]);
#pragma unroll
      for (int nt = 0; nt < 4; ++nt)
        acc[mt][nt] = __builtin_amdgcn_mfma_f32_16x16x32_bf16(af, wf[nt], acc[mt][nt], 0, 0, 0);
    }
    __syncthreads();
  }
  int rq = (lane >> 4) * 4, cl = lane & 15;
#pragma unroll
  for (int mt = 0; mt < 4; ++mt) {
#pragma unroll
    for (int nt = 0; nt < 4; ++nt) {
#pragma unroll
      for (int rg = 0; rg < 4; ++rg) {
        int row = m0 + wm + mt * 16 + rq + rg;
        int col = n0 + wn + nt * 16 + cl;
        float v = acc[mt][nt][rg];
        if (MODE == 1) {
          ((float*)Cout)[(long)bz * sCb + (long)row * ldc + col] = v * scale;
        } else if (MODE == 2) {
          ((u16*)Cout)[(long)bz * sCb + (long)row * ldc + col] = f2bf(v);
        } else if (MODE == 3) {
          float mk = (bf2f(maskSrc[(long)row * D_]) != 0.f) ? 1.f : 0.f;
          ((u16*)Cout)[(long)row * ldc + col] = f2bf(tanhf(v + bias[col]) * mk);
        } else {
          if (col < N) {
            float mk = (bf2f(maskSrc[(long)row * D_]) != 0.f) ? 1.f : 0.f;
            ((float*)Cout)[(long)row * ldc + col] = (v + bias[col]) * mk;
          }
        }
      }
    }
  }
}

// ---------------- wavefront-pipelined 3-layer GRU, write-once ring ----------------
// grid 192 = l(3) x bg(4) x cg(16); 512 thr = 8 waves (gh: nh x kh, xp: nh x kh).
// Phase t: gh consumes sXP[t&1]; xp prepares xp[t+1] into sXP[(t+1)&1].
// ring(l,t): one 128KB slot per (layer, step), WRITTEN ONCE via WT atomics; consumers
// use cached volatile-asm loads (safe: write-once addresses; launch acquire handles
// replays). No WAR poll. flags padded 64B/flag; wave-0-only poll (own & below).
__global__ __launch_bounds__(512, 1) void gru_wave(
    const int* __restrict__ tok, const float* __restrict__ embedding,
    const u16* __restrict__ wih_all, const u16* __restrict__ whh_all,
    const float* __restrict__ bih_all, const float* __restrict__ bhh_all,
    const float* __restrict__ hidden,
    unsigned* __restrict__ ring01, unsigned* __restrict__ ring2,
    unsigned* __restrict__ ringM1, unsigned* __restrict__ flags,
    u16* __restrict__ xout2, float* __restrict__ hfin) {
  __shared__ u16 sHA[32 * 512];
  __shared__ u16 sHB[32 * 512];
  __shared__ float sXP[2][32 * 101];
  __shared__ float sPART[24 * 272];
  const int bid = blockIdx.x;
  const int l = bid >> 6;
  const int bg = (bid >> 4) & 3;
  const int cg = bid & 15;
  const int tid = threadIdx.x;
  const int wave = tid >> 6;          // 0..7
  const bool isXp = wave >= 4;
  const int nh = (wave >> 1) & 1;
  const int kh = wave & 1;
  const int lane = tid & 63;
  const int rr = lane & 15, kq = lane >> 4;
  const int cl = rr, rq = kq;
  const int chL = nh * 16 + cl;
  const int ch = cg * 32 + chL;       // this thread's output channel
  unsigned* myflags = flags + (l * 64 + bg * 16) * 16;
  const unsigned* belowflags = (l > 0) ? flags + ((l - 1) * 64 + bg * 16) * 16 : myflags;
  const u16* Wsrc = (isXp ? wih_all : whh_all) + (long)l * 786432;
  const float* bsrc = (isXp ? bih_all : bhh_all) + l * 1536;
  float bh[3];
#pragma unroll
  for (int g = 0; g < 3; ++g) bh[g] = bsrc[g * 512 + ch];

  // write-once ring addressing: 32768 u32 (128KB) per (layer, step)
  auto ringAddr = [&](int lay, int t) -> unsigned* {
    if (t < 0) return ringM1 + lay * 32768;
    if (lay == 2) return ring2 + (long)t * 32768;
    return ring01 + ((long)lay * 512 + t) * 32768;
  };

  // --- this wave's K-half weight fragments: 24 x u32x4 (L2-streamed per phase) ---
  u32x4 wf[3][8];
#pragma unroll
  for (int g = 0; g < 3; ++g) {
    const u16* wrow =
        Wsrc + ((long)(g * 512 + cg * 32 + nh * 16 + rr)) * 512 + kh * 256 + kq * 8;
#pragma unroll
    for (int ks = 0; ks < 8; ++ks) wf[g][ks] = *(const u32x4*)(wrow + ks * 32);
  }

  // --- fp32 master h (gh kh0 only) ---
  float mh[2][4] = {};
  if (!isXp && kh == 0) {
#pragma unroll
    for (int mt = 0; mt < 2; ++mt)
#pragma unroll
      for (int rg = 0; rg < 4; ++rg)
        mh[mt][rg] =
            hidden[(long)l * 65536 + (long)(bg * 32 + mt * 16 + rq * 4 + rg) * 512 + ch];
  }

#pragma unroll 1
  for (int t = -1; t < S_; ++t) {
    const bool doXp = isXp && (t < S_ - 1);
    // in-loop pin (keeps wf materialization near the top of the phase)
#pragma unroll
    for (int g = 0; g < 3; ++g)
#pragma unroll
      for (int ks = 0; ks < 8; ++ks) asm volatile("" : "+v"(wf[g][ks]));

    // --- layer-0 xp: stage embedding rows for step t+1 (flag-independent; overlaps poll) ---
    if (doXp && l == 0) {
      int u = tid - 256;
#pragma unroll
      for (int i = 0; i < 2; ++i) {
        int task = u + i * 256;
        int row = task >> 4;
        int c0 = (task & 15) * 32;
        int tk = tok[(long)(bg * 32 + row) * 512 + (t + 1)];
        const float* es = embedding + (long)tk * 512 + c0;
        u16 tmp[32];
#pragma unroll
        for (int q = 0; q < 8; ++q) {
          float4 v = *(const float4*)(es + q * 4);
          tmp[q * 4 + 0] = f2bf(v.x); tmp[q * 4 + 1] = f2bf(v.y);
          tmp[q * 4 + 2] = f2bf(v.z); tmp[q * 4 + 3] = f2bf(v.w);
        }
#pragma unroll
        for (int q = 0; q < 4; ++q) {
          int grp = (c0 >> 3) + q;
          *(u32x4*)&sHB[row * 512 + ((grp ^ (row & 7)) * 8)] = *(u32x4*)&tmp[q * 8];
        }
      }
    }
    asm volatile("" ::: "memory");
    // --- SINGLE polling wave (wave 0): own >= t+1 (lanes 0-15), below >= t+3 (lanes 32-47) ---
    if (wave == 0) {
      const int grp = lane >> 4;            // 0..3
      const unsigned* fp = nullptr;
      int tgt = 0;
      if (grp == 0) { fp = myflags + (lane & 15) * 16; tgt = t + 1; }
      else if (grp == 2 && l > 0 && t < S_ - 1) { fp = belowflags + (lane & 15) * 16; tgt = t + 3; }
      int it = 0;
      bool ok;
      do {
        int v = fp ? (int)__hip_atomic_load(fp, __ATOMIC_RELAXED, __HIP_MEMORY_SCOPE_AGENT)
                   : 0x3fffffff;
        ok = (bool)__all(v >= tgt);
        if (!ok) __builtin_amdgcn_s_sleep(1);
      } while (!ok && ++it < (1 << 22));
    }
    __syncthreads();                                   // B0: all conditions met
    // --- stage h slices (CACHED loads from write-once ring) ---
    if (!isXp && t >= 0) {
      const unsigned* hsrc = ringAddr(l, t - 1) + bg * 32 * 256;
      u32x4 vv[8];
#pragma unroll
      for (int i = 0; i < 8; ++i) {
        int uu = tid + i * 256;
        const unsigned* src = hsrc + (uu >> 6) * 256 + (uu & 63) * 4;
        asm volatile("global_load_dwordx4 %0, %1, off"
                     : "=&v"(vv[i]) : "v"(src) : "memory");
      }
      asm volatile("s_waitcnt vmcnt(0)" ::: "memory");
      __builtin_amdgcn_sched_barrier(0);
#pragma unroll
      for (int i = 0; i < 8; ++i) {
        int uu = tid + i * 256;
        int row = uu >> 6, c8 = uu & 63;
        *(u32x4*)&sHA[row * 512 + ((c8 ^ (row & 7)) * 8)] = vv[i];
      }
    } else if (doXp && l > 0) {
      const unsigned* hsrc = ringAddr(l - 1, t + 1) + bg * 32 * 256;
      u32x4 vv[8];
#pragma unroll
      for (int i = 0; i < 8; ++i) {
        int uu = (tid - 256) + i * 256;
        const unsigned* src = hsrc + (uu >> 6) * 256 + (uu & 63) * 4;
        asm volatile("global_load_dwordx4 %0, %1, off"
                     : "=&v"(vv[i]) : "v"(src) : "memory");
      }
      asm volatile("s_waitcnt vmcnt(0)" ::: "memory");
      __builtin_amdgcn_sched_barrier(0);
#pragma unroll
      for (int i = 0; i < 8; ++i) {
        int uu = (tid - 256) + i * 256;
        int row = uu >> 6, c8 = uu & 63;
        *(u32x4*)&sHB[row * 512 + ((c8 ^ (row & 7)) * 8)] = vv[i];
      }
    }
    __syncthreads();                                   // B1
    // --- MFMA: 2 M-tiles x 3 gates x K-half(256) ---
    f32x4 acc[2][3] = {};
    const bool doMM = isXp ? doXp : (t >= 0);
    if (doMM) {
      const u16* sH = isXp ? sHB : sHA;
#pragma unroll
      for (int mt = 0; mt < 2; ++mt) {
        const int abase = (mt * 16 + rr) * 512;
        const int axor = (mt * 16 + rr) & 7;
#pragma unroll
        for (int ks = 0; ks < 8; ++ks) {
          const int grp = kh * 32 + ks * 4 + kq;
          bf16x8 af = __builtin_bit_cast(
              bf16x8, *(const u32x4*)&sH[abase + ((grp ^ axor) * 8)]);
#pragma unroll
          for (int g = 0; g < 3; ++g)
            acc[mt][g] = __builtin_amdgcn_mfma_f32_16x16x32_bf16(
                af, __builtin_bit_cast(bf16x8, wf[g][ks]), acc[mt][g], 0, 0, 0);
        }
      }
      if (kh == 1) {
#pragma unroll
        for (int mt = 0; mt < 2; ++mt)
#pragma unroll
          for (int g = 0; g < 3; ++g) {
            float* sp = &sPART[((((isXp ? 2 : 0) + nh) * 2 + mt) * 3 + g) * 272];
#pragma unroll
            for (int rg = 0; rg < 4; ++rg)
              sp[(rq * 4 + rg) * 17 + cl] = acc[mt][g][rg];
          }
      }
    }
    __syncthreads();                                   // B2
    if (doMM && kh == 0) {
#pragma unroll
      for (int mt = 0; mt < 2; ++mt)
#pragma unroll
        for (int g = 0; g < 3; ++g) {
          const float* sp = &sPART[((((isXp ? 2 : 0) + nh) * 2 + mt) * 3 + g) * 272];
#pragma unroll
          for (int rg = 0; rg < 4; ++rg)
            acc[mt][g][rg] += sp[(rq * 4 + rg) * 17 + cl];
        }
      if (isXp) {
        float* xpd = sXP[(t + 1) & 1];
#pragma unroll
        for (int mt = 0; mt < 2; ++mt)
#pragma unroll
          for (int g = 0; g < 3; ++g)
#pragma unroll
            for (int rg = 0; rg < 4; ++rg)
              xpd[(mt * 16 + rq * 4 + rg) * 101 + g * 32 + chL] =
                  acc[mt][g][rg] + bh[g];
      }
    }
    // --- gh gates (reads sXP[t&1], written at phase t-1) + publish ring(l,t) ---
    unsigned xsv[2][4];
    if (!isXp && kh == 0) {
      const float* xps = sXP[t & 1];
      unsigned* rdst = ringAddr(l, t);
#pragma unroll
      for (int mt = 0; mt < 2; ++mt) {
        unsigned pk[4];
#pragma unroll
        for (int rg = 0; rg < 4; ++rg) {
          float h2;
          if (t >= 0) {
            int rloc = mt * 16 + rq * 4 + rg;
            float xr = xps[rloc * 101 + chL];
            float xz = xps[rloc * 101 + 32 + chL];
            float xn = xps[rloc * 101 + 64 + chL];
            float r = 1.f / (1.f + __expf(-(xr + acc[mt][0][rg] + bh[0])));
            float z = 1.f / (1.f + __expf(-(xz + acc[mt][1][rg] + bh[1])));
            float n = tanhf(xn + r * (acc[mt][2][rg] + bh[2]));
            h2 = (1.f - z) * n + z * mh[mt][rg];
            mh[mt][rg] = h2;
          } else {
            h2 = mh[mt][rg];   // t=-1: publish initial hidden state
          }
          pk[rg] = (unsigned)f2bf(h2);
        }
        xsv[mt][0] = pk[0]; xsv[mt][1] = pk[1]; xsv[mt][2] = pk[2]; xsv[mt][3] = pk[3];
#pragma unroll
        for (int rg = 0; rg < 4; ++rg) {
          unsigned prt = (unsigned)__shfl_xor((int)pk[rg], 1);
          if (!(cl & 1))
            __hip_atomic_store(
                &rdst[(bg * 32 + mt * 16 + rq * 4 + rg) * 256 + (ch >> 1)],
                pk[rg] | (prt << 16), __ATOMIC_RELAXED, __HIP_MEMORY_SCOPE_AGENT);
        }
      }
      asm volatile("s_waitcnt vmcnt(0)" ::: "memory");   // ring data at IC
    }
    __syncthreads();                                   // B3: publishes + sXP write done
    if (tid == 0)
      __hip_atomic_store(&myflags[cg * 16], (unsigned)(t + 2), __ATOMIC_RELAXED,
                         __HIP_MEMORY_SCOPE_AGENT);
    // l=2 output stores AFTER the flag: off the handshake critical path
    if (l == 2 && t >= 0 && !isXp && kh == 0) {
#pragma unroll
      for (int mt = 0; mt < 2; ++mt)
#pragma unroll
        for (int rg = 0; rg < 4; ++rg) {
          int rloc = mt * 16 + rq * 4 + rg;
          xout2[((long)(bg * 32 + rloc) * 512 + t) * 512 + ch] = (u16)xsv[mt][rg];
        }
    }
  }
  if (!isXp && kh == 0) {
#pragma unroll
    for (int mt = 0; mt < 2; ++mt)
#pragma unroll
      for (int rg = 0; rg < 4; ++rg)
        hfin[(long)l * 65536 + (long)(bg * 32 + mt * 16 + rq * 4 + rg) * 512 + ch] =
            mh[mt][rg];
  }
}

extern "C" void kernel_launch(void* const* d_in, const int* in_sizes, int n_in,
                              void* d_out, int out_size, void* d_ws, size_t ws_size,
                              hipStream_t stream) {
  const int* padded    = (const int*)d_in[0];
  const float* enc     = (const float*)d_in[2];
  const float* hidden  = (const float*)d_in[3];
  const float* embedding = (const float*)d_in[4];
  const float* w_ih    = (const float*)d_in[5];
  const float* w_hh    = (const float*)d_in[6];
  const float* b_ih    = (const float*)d_in[7];
  const float* b_hh    = (const float*)d_in[8];
  const float* attn_w  = (const float*)d_in[9];
  const float* attn_b  = (const float*)d_in[10];
  const float* out_w   = (const float*)d_in[11];
  const float* out_b   = (const float*)d_in[12];

  if (ws_size < 280645632ULL) return;   // ws budget guard

  char* ws = (char*)d_ws;
  u16* W_IH   = (u16*)(ws + 0);               // 3*1536*512 bf16
  u16* W_HH   = (u16*)(ws + 4718592);
  u16* ATTN_W = (u16*)(ws + 9437184);         // 512*1024 bf16
  u16* OUT_W  = (u16*)(ws + 10485760);        // 100*512 bf16
  unsigned* FLAGS = (unsigned*)(ws + 10588160);   // 3*64 flags x 16 u32 pad = 48 KB
  unsigned* RINGM1 = (unsigned*)(ws + 10637312);  // 3 x 128KB h[-1] slots (1.5MB rsvd)
  u16* XA     = (u16*)(ws + 12210176);        // context bf16 (64 MB); ring2 during GRU
  u16* XB     = (u16*)(ws + 79319040);        // dec = layer-2 output, 64 MB
  u16* ENCT   = (u16*)(ws + 146427904);       // enc^T bf16, 64 MB
  u16* AMASK  = (u16*)(ws + 213536768);       // tanh-masked / softmax-bf16 alias, 64 MB
  u16* ATTN_BF = AMASK;

  float* out_logits = (float*)d_out;                 // 65536*100
  float* out_h      = out_logits + 6553600;          // 3*128*512
  float* out_attn   = out_h + 196608;                // 128*512*512; ring01 during GRU

  unsigned* RING01 = (unsigned*)out_attn;            // L0/L1 trajectories, 2*512*128KB
  unsigned* RING2  = (unsigned*)XA;                  // L2 trajectory, 512*128KB

  zero_flags<<<12, 256, 0, stream>>>(FLAGS, 3072);
  cvt_f32_bf16<<<512, 256, 0, stream>>>(w_ih, W_IH, 2359296 / 4);
  cvt_f32_bf16<<<512, 256, 0, stream>>>(w_hh, W_HH, 2359296 / 4);
  cvt_f32_bf16<<<256, 256, 0, stream>>>(attn_w, ATTN_W, 524288 / 4);
  cvt_f32_bf16<<<64, 256, 0, stream>>>(out_w, OUT_W, 51200 / 4);
  transpose_enc<<<dim3(8, 8, 128), 256, 0, stream>>>(enc, ENCT);

  gru_wave<<<192, 512, 0, stream>>>(
      padded, embedding, W_IH, W_HH, b_ih, b_hh, hidden,
      RING01, RING2, RINGM1, FLAGS, XB, out_h);

  // attention (scores GEMM converts f32 enc in staging; overwrites ring01 region)
  gemm_xwt<1, 1><<<dim3(4, 4, 128), 256, 0, stream>>>(
      XB, nullptr, (const u16*)enc, nullptr, out_attn, nullptr,
      512, 512, 512, 262144, 262144, 262144, 0.044194173824159216f, 512);
  softmax_rows<<<16384, 256, 0, stream>>>(out_attn, ATTN_BF);
  gemm_xwt<2, 0><<<dim3(4, 4, 128), 256, 0, stream>>>(
      ATTN_BF, nullptr, ENCT, nullptr, XA, nullptr,
      512, 512, 512, 262144, 262144, 262144, 1.f, 512);
  gemm_xwt<3, 0><<<dim3(4, 512, 1), 256, 0, stream>>>(
      XB, XA, ATTN_W, attn_b, AMASK, XB,
      512, 1024, 512, 0, 0, 0, 1.f, 512);
  gemm_xwt<4, 0><<<dim3(1, 512, 1), 256, 0, stream>>>(
      AMASK, nullptr, OUT_W, out_b, d_out, XB,
      100, 512, 512, 0, 0, 0, 1.f, 100);
}

// Round 13
// 3319.090 us; speedup vs baseline: 1.1624x; 1.1624x over previous
//
#include <hip/hip_runtime.h>

// Decoder: emb -> 3-layer GRU -> scaled-dot attention over encoder -> tanh(linear) -> logits
// Round 12: early per-wave flags + B3 deleted (4 -> 3 barriers/phase).
//   r11 post-mortem: cached-ring neutral -> consumer reads not the bottleneck. Remaining
//   slack: flag was stored by tid0 AFTER B3 (waits for all 8 waves incl. irrelevant xp).
//   Now: 32 flags/(l,bg) family (one per gh-kh0 wave x nh), stored by the producing wave
//   right after its own vmcnt(0) drain. Poll: lanes 0-31 own(32 flags), 32-63 below(32).
//   Write-once ring kept (no WAR poll); bypass sc0 sc1 loads restored (r10 mode).

typedef unsigned short u16;
typedef __attribute__((ext_vector_type(8))) __bf16 bf16x8;
typedef __attribute__((ext_vector_type(4))) float f32x4;
typedef __attribute__((ext_vector_type(4))) unsigned int u32x4;

#define D_ 512
#define S_ 512
#define SE_ 512
#define B_ 128
#define V_ 100

__device__ __forceinline__ float bf2f(u16 v) {
  unsigned u = ((unsigned)v) << 16;
  return __builtin_bit_cast(float, u);
}
__device__ __forceinline__ u16 f2bf(float f) {
  unsigned u = __builtin_bit_cast(unsigned, f);
  u += 0x7FFF + ((u >> 16) & 1);   // RNE
  return (u16)(u >> 16);
}

// ---------------- elementwise converts ----------------
__global__ __launch_bounds__(256) void cvt_f32_bf16(const float* __restrict__ src,
                                                    u16* __restrict__ dst, long n4) {
  long i = (long)blockIdx.x * 256 + threadIdx.x;
  long stride = (long)gridDim.x * 256;
  for (; i < n4; i += stride) {
    float4 v = ((const float4*)src)[i];
    unsigned long long p = (unsigned long long)f2bf(v.x) |
                           ((unsigned long long)f2bf(v.y) << 16) |
                           ((unsigned long long)f2bf(v.z) << 32) |
                           ((unsigned long long)f2bf(v.w) << 48);
    ((unsigned long long*)dst)[i] = p;
  }
}

__global__ __launch_bounds__(256) void zero_flags(unsigned* __restrict__ f, int n) {
  int i = blockIdx.x * 256 + threadIdx.x;
  if (i < n)
    __hip_atomic_store(&f[i], 0u, __ATOMIC_RELAXED, __HIP_MEMORY_SCOPE_AGENT);
}

// enc (B,SE,D) f32 -> encT (B,D,SE) bf16
__global__ __launch_bounds__(256) void transpose_enc(const float* __restrict__ enc,
                                                     u16* __restrict__ encT) {
  __shared__ u16 tile[64][72];
  int b = blockIdx.z, d0 = blockIdx.x * 64, se0 = blockIdx.y * 64;
  const float* src = enc + (long)b * SE_ * D_;
  int t = threadIdx.x;
  int r = t >> 2, cq = (t & 3) * 16;
#pragma unroll
  for (int j = 0; j < 4; ++j) {
    float4 v = *(const float4*)(src + (long)(se0 + r) * D_ + d0 + cq + j * 4);
    tile[r][cq + j * 4 + 0] = f2bf(v.x);
    tile[r][cq + j * 4 + 1] = f2bf(v.y);
    tile[r][cq + j * 4 + 2] = f2bf(v.z);
    tile[r][cq + j * 4 + 3] = f2bf(v.w);
  }
  __syncthreads();
  u16* dst = encT + (long)b * D_ * SE_;
  u16 ov[16];
#pragma unroll
  for (int j = 0; j < 16; ++j) ov[j] = tile[cq + j][r];
  *(u32x4*)(dst + (long)(d0 + r) * SE_ + se0 + cq) = *(u32x4*)&ov[0];
  *(u32x4*)(dst + (long)(d0 + r) * SE_ + se0 + cq + 8) = *(u32x4*)&ov[8];
}

// in-place fp32 softmax over 512-wide rows + bf16 copy
__global__ __launch_bounds__(256) void softmax_rows(float* __restrict__ sc,
                                                    u16* __restrict__ abf) {
  long row = (long)blockIdx.x * 4 + (threadIdx.x >> 6);
  int lane = threadIdx.x & 63;
  float* p = sc + row * 512;
  float4 v0 = ((const float4*)p)[lane * 2];
  float4 v1 = ((const float4*)p)[lane * 2 + 1];
  float vals[8] = {v0.x, v0.y, v0.z, v0.w, v1.x, v1.y, v1.z, v1.w};
  float m = vals[0];
#pragma unroll
  for (int j = 1; j < 8; ++j) m = fmaxf(m, vals[j]);
#pragma unroll
  for (int o = 32; o; o >>= 1) m = fmaxf(m, __shfl_xor(m, o, 64));
  float s = 0.f;
#pragma unroll
  for (int j = 0; j < 8; ++j) { vals[j] = __expf(vals[j] - m); s += vals[j]; }
#pragma unroll
  for (int o = 32; o; o >>= 1) s += __shfl_xor(s, o, 64);
  float inv = 1.f / s;
  u16 ob[8];
#pragma unroll
  for (int j = 0; j < 8; ++j) { vals[j] *= inv; ob[j] = f2bf(vals[j]); }
  float4 w0 = {vals[0], vals[1], vals[2], vals[3]};
  float4 w1 = {vals[4], vals[5], vals[6], vals[7]};
  ((float4*)p)[lane * 2] = w0;
  ((float4*)p)[lane * 2 + 1] = w1;
  *(u32x4*)(abf + row * 512 + lane * 8) = *(u32x4*)ob;
}

// ---------------- generic C = A(M,K) @ W(N,K)^T, bf16 in / f32 acc ----------------
template <int MODE, int WF32>
__global__ __launch_bounds__(256) void gemm_xwt(
    const u16* __restrict__ A1, const u16* __restrict__ A2, const u16* __restrict__ W,
    const float* __restrict__ bias, void* __restrict__ Cout, const u16* __restrict__ maskSrc,
    int N, int K, int K1, long sAb, long sWb, long sCb, float scale, int ldc) {
  __shared__ u16 sA[128][32];
  __shared__ u16 sW_[128][32];
  int bz = blockIdx.z;
  int n0 = blockIdx.x * 128, m0 = blockIdx.y * 128;
  const u16* Ab = A1 + (long)bz * sAb;
  int t = threadIdx.x, wave = t >> 6, lane = t & 63;
  int wm = (wave >> 1) * 64, wn = (wave & 1) * 64;
  f32x4 acc[4][4] = {};
  for (int kk = 0; kk < K; kk += 32) {
#pragma unroll
    for (int i = 0; i < 2; ++i) {
      int id = t + i * 256;
      int row = id >> 2, c8 = (id & 3) * 8;
      const u16* src;
      if (MODE == 3 && kk >= K1)
        src = A2 + (long)(m0 + row) * (K - K1) + (kk - K1) + c8;
      else
        src = Ab + (long)(m0 + row) * K1 + kk + c8;
      *(u32x4*)&sA[row][c8] = *(const u32x4*)src;
    }
#pragma unroll
    for (int i = 0; i < 2; ++i) {
      int id = t + i * 256;
      int row = id >> 2, c8 = (id & 3) * 8;
      if (WF32) {
        const float* wsrc = ((const float*)W) + (long)bz * sWb + (long)(n0 + row) * K + kk + c8;
        float4 va = *(const float4*)wsrc;
        float4 vb = *(const float4*)(wsrc + 4);
        u16 tmp[8] = {f2bf(va.x), f2bf(va.y), f2bf(va.z), f2bf(va.w),
                      f2bf(vb.x), f2bf(vb.y), f2bf(vb.z), f2bf(vb.w)};
        *(u32x4*)&sW_[row][c8] = *(u32x4*)tmp;
      } else {
        u32x4 v = {0u, 0u, 0u, 0u};
        if (n0 + row < N) v = *(const u32x4*)(W + (long)bz * sWb + (long)(n0 + row) * K + kk + c8);
        *(u32x4*)&sW_[row][c8] = v;
      }
    }
    __syncthreads();
    int k8 = (lane >> 4) * 8, rr = lane & 15;
    bf16x8 wf[4];
#pragma unroll
    for (int nt = 0; nt < 4; ++nt)
      wf[nt] = __builtin_bit_cast(bf16x8, *(const u32x4*)&sW_[wn + nt * 16 + rr][k8]);
#pragma unroll
    for (int mt = 0; mt < 4; ++mt) {
      bf16x8 af = __builtin_bit_cast(bf16x8, *(const u32x4*)&sA[wm + mt * 16 + rr][k8]);
#pragma unroll
      for (int nt = 0; nt < 4; ++nt)
        acc[mt][nt] = __builtin_amdgcn_mfma_f32_16x16x32_bf16(af, wf[nt], acc[mt][nt], 0, 0, 0);
    }
    __syncthreads();
  }
  int rq = (lane >> 4) * 4, cl = lane & 15;
#pragma unroll
  for (int mt = 0; mt < 4; ++mt) {
#pragma unroll
    for (int nt = 0; nt < 4; ++nt) {
#pragma unroll
      for (int rg = 0; rg < 4; ++rg) {
        int row = m0 + wm + mt * 16 + rq + rg;
        int col = n0 + wn + nt * 16 + cl;
        float v = acc[mt][nt][rg];
        if (MODE == 1) {
          ((float*)Cout)[(long)bz * sCb + (long)row * ldc + col] = v * scale;
        } else if (MODE == 2) {
          ((u16*)Cout)[(long)bz * sCb + (long)row * ldc + col] = f2bf(v);
        } else if (MODE == 3) {
          float mk = (bf2f(maskSrc[(long)row * D_]) != 0.f) ? 1.f : 0.f;
          ((u16*)Cout)[(long)row * ldc + col] = f2bf(tanhf(v + bias[col]) * mk);
        } else {
          if (col < N) {
            float mk = (bf2f(maskSrc[(long)row * D_]) != 0.f) ? 1.f : 0.f;
            ((float*)Cout)[(long)row * ldc + col] = (v + bias[col]) * mk;
          }
        }
      }
    }
  }
}

// ---------------- wavefront-pipelined 3-layer GRU, write-once ring, early flags ----------------
// grid 192 = l(3) x bg(4) x cg(16); 512 thr = 8 waves (gh: nh x kh, xp: nh x kh).
// Phase t: gh consumes sXP[t&1]; xp prepares xp[t+1] into sXP[(t+1)&1].
// flags: 32 per (l,bg) family (one per (cg,nh) producer wave), 64B line each; stored by
// each gh-kh0 wave right after ITS OWN vmcnt drain (no trailing barrier). 3 barriers/phase.
// Poll (wave 0): lanes 0-31 own 32 flags >= t+1; lanes 32-63 below 32 flags >= t+3.
__global__ __launch_bounds__(512, 1) void gru_wave(
    const int* __restrict__ tok, const float* __restrict__ embedding,
    const u16* __restrict__ wih_all, const u16* __restrict__ whh_all,
    const float* __restrict__ bih_all, const float* __restrict__ bhh_all,
    const float* __restrict__ hidden,
    unsigned* __restrict__ ring01, unsigned* __restrict__ ring2,
    unsigned* __restrict__ ringM1, unsigned* __restrict__ flags,
    u16* __restrict__ xout2, float* __restrict__ hfin) {
  __shared__ u16 sHA[32 * 512];
  __shared__ u16 sHB[32 * 512];
  __shared__ float sXP[2][32 * 101];
  __shared__ float sPART[24 * 272];
  const int bid = blockIdx.x;
  const int l = bid >> 6;
  const int bg = (bid >> 4) & 3;
  const int cg = bid & 15;
  const int tid = threadIdx.x;
  const int wave = tid >> 6;          // 0..7
  const bool isXp = wave >= 4;
  const int nh = (wave >> 1) & 1;
  const int kh = wave & 1;
  const int lane = tid & 63;
  const int rr = lane & 15, kq = lane >> 4;
  const int cl = rr, rq = kq;
  const int chL = nh * 16 + cl;
  const int ch = cg * 32 + chL;       // this thread's output channel
  unsigned* myflags = flags + (l * 4 + bg) * 32 * 16;
  const unsigned* belowflags = (l > 0) ? flags + ((l - 1) * 4 + bg) * 32 * 16 : myflags;
  const u16* Wsrc = (isXp ? wih_all : whh_all) + (long)l * 786432;
  const float* bsrc = (isXp ? bih_all : bhh_all) + l * 1536;
  float bh[3];
#pragma unroll
  for (int g = 0; g < 3; ++g) bh[g] = bsrc[g * 512 + ch];

  // write-once ring addressing: 32768 u32 (128KB) per (layer, step)
  auto ringAddr = [&](int lay, int t) -> unsigned* {
    if (t < 0) return ringM1 + lay * 32768;
    if (lay == 2) return ring2 + (long)t * 32768;
    return ring01 + ((long)lay * 512 + t) * 32768;
  };

  // --- this wave's K-half weight fragments: 24 x u32x4 (L2-streamed per phase) ---
  u32x4 wf[3][8];
#pragma unroll
  for (int g = 0; g < 3; ++g) {
    const u16* wrow =
        Wsrc + ((long)(g * 512 + cg * 32 + nh * 16 + rr)) * 512 + kh * 256 + kq * 8;
#pragma unroll
    for (int ks = 0; ks < 8; ++ks) wf[g][ks] = *(const u32x4*)(wrow + ks * 32);
  }

  // --- fp32 master h (gh kh0 only) ---
  float mh[2][4] = {};
  if (!isXp && kh == 0) {
#pragma unroll
    for (int mt = 0; mt < 2; ++mt)
#pragma unroll
      for (int rg = 0; rg < 4; ++rg)
        mh[mt][rg] =
            hidden[(long)l * 65536 + (long)(bg * 32 + mt * 16 + rq * 4 + rg) * 512 + ch];
  }

#pragma unroll 1
  for (int t = -1; t < S_; ++t) {
    const bool doXp = isXp && (t < S_ - 1);
    // in-loop pin (keeps wf materialization near the top of the phase)
#pragma unroll
    for (int g = 0; g < 3; ++g)
#pragma unroll
      for (int ks = 0; ks < 8; ++ks) asm volatile("" : "+v"(wf[g][ks]));

    // --- layer-0 xp: stage embedding rows for step t+1 (flag-independent; overlaps poll) ---
    if (doXp && l == 0) {
      int u = tid - 256;
#pragma unroll
      for (int i = 0; i < 2; ++i) {
        int task = u + i * 256;
        int row = task >> 4;
        int c0 = (task & 15) * 32;
        int tk = tok[(long)(bg * 32 + row) * 512 + (t + 1)];
        const float* es = embedding + (long)tk * 512 + c0;
        u16 tmp[32];
#pragma unroll
        for (int q = 0; q < 8; ++q) {
          float4 v = *(const float4*)(es + q * 4);
          tmp[q * 4 + 0] = f2bf(v.x); tmp[q * 4 + 1] = f2bf(v.y);
          tmp[q * 4 + 2] = f2bf(v.z); tmp[q * 4 + 3] = f2bf(v.w);
        }
#pragma unroll
        for (int q = 0; q < 4; ++q) {
          int grp = (c0 >> 3) + q;
          *(u32x4*)&sHB[row * 512 + ((grp ^ (row & 7)) * 8)] = *(u32x4*)&tmp[q * 8];
        }
      }
    }
    asm volatile("" ::: "memory");
    // --- SINGLE polling wave: lanes 0-31 own(32 flags) >= t+1; 32-63 below >= t+3 ---
    if (wave == 0) {
      const unsigned* fp = nullptr;
      int tgt = 0;
      if (lane < 32) { fp = myflags + lane * 16; tgt = t + 1; }
      else if (l > 0 && t < S_ - 1) { fp = belowflags + (lane - 32) * 16; tgt = t + 3; }
      int it = 0;
      bool ok;
      do {
        int v = fp ? (int)__hip_atomic_load(fp, __ATOMIC_RELAXED, __HIP_MEMORY_SCOPE_AGENT)
                   : 0x3fffffff;
        ok = (bool)__all(v >= tgt);
        if (!ok) __builtin_amdgcn_s_sleep(1);
      } while (!ok && ++it < (1 << 22));
    }
    __syncthreads();                                   // B0: all conditions met
    // --- stage h slices (bypass loads from write-once ring) ---
    if (!isXp && t >= 0) {
      const unsigned* hsrc = ringAddr(l, t - 1) + bg * 32 * 256;
      u32x4 vv[8];
#pragma unroll
      for (int i = 0; i < 8; ++i) {
        int uu = tid + i * 256;
        const unsigned* src = hsrc + (uu >> 6) * 256 + (uu & 63) * 4;
        asm volatile("global_load_dwordx4 %0, %1, off sc0 sc1"
                     : "=&v"(vv[i]) : "v"(src) : "memory");
      }
      asm volatile("s_waitcnt vmcnt(0)" ::: "memory");
      __builtin_amdgcn_sched_barrier(0);
#pragma unroll
      for (int i = 0; i < 8; ++i) {
        int uu = tid + i * 256;
        int row = uu >> 6, c8 = uu & 63;
        *(u32x4*)&sHA[row * 512 + ((c8 ^ (row & 7)) * 8)] = vv[i];
      }
    } else if (doXp && l > 0) {
      const unsigned* hsrc = ringAddr(l - 1, t + 1) + bg * 32 * 256;
      u32x4 vv[8];
#pragma unroll
      for (int i = 0; i < 8; ++i) {
        int uu = (tid - 256) + i * 256;
        const unsigned* src = hsrc + (uu >> 6) * 256 + (uu & 63) * 4;
        asm volatile("global_load_dwordx4 %0, %1, off sc0 sc1"
                     : "=&v"(vv[i]) : "v"(src) : "memory");
      }
      asm volatile("s_waitcnt vmcnt(0)" ::: "memory");
      __builtin_amdgcn_sched_barrier(0);
#pragma unroll
      for (int i = 0; i < 8; ++i) {
        int uu = (tid - 256) + i * 256;
        int row = uu >> 6, c8 = uu & 63;
        *(u32x4*)&sHB[row * 512 + ((c8 ^ (row & 7)) * 8)] = vv[i];
      }
    }
    __syncthreads();                                   // B1
    // --- MFMA: 2 M-tiles x 3 gates x K-half(256) ---
    f32x4 acc[2][3] = {};
    const bool doMM = isXp ? doXp : (t >= 0);
    if (doMM) {
      const u16* sH = isXp ? sHB : sHA;
#pragma unroll
      for (int mt = 0; mt < 2; ++mt) {
        const int abase = (mt * 16 + rr) * 512;
        const int axor = (mt * 16 + rr) & 7;
#pragma unroll
        for (int ks = 0; ks < 8; ++ks) {
          const int grp = kh * 32 + ks * 4 + kq;
          bf16x8 af = __builtin_bit_cast(
              bf16x8, *(const u32x4*)&sH[abase + ((grp ^ axor) * 8)]);
#pragma unroll
          for (int g = 0; g < 3; ++g)
            acc[mt][g] = __builtin_amdgcn_mfma_f32_16x16x32_bf16(
                af, __builtin_bit_cast(bf16x8, wf[g][ks]), acc[mt][g], 0, 0, 0);
        }
      }
      if (kh == 1) {
#pragma unroll
        for (int mt = 0; mt < 2; ++mt)
#pragma unroll
          for (int g = 0; g < 3; ++g) {
            float* sp = &sPART[((((isXp ? 2 : 0) + nh) * 2 + mt) * 3 + g) * 272];
#pragma unroll
            for (int rg = 0; rg < 4; ++rg)
              sp[(rq * 4 + rg) * 17 + cl] = acc[mt][g][rg];
          }
      }
    }
    __syncthreads();                                   // B2
    if (doMM && kh == 0) {
#pragma unroll
      for (int mt = 0; mt < 2; ++mt)
#pragma unroll
        for (int g = 0; g < 3; ++g) {
          const float* sp = &sPART[((((isXp ? 2 : 0) + nh) * 2 + mt) * 3 + g) * 272];
#pragma unroll
          for (int rg = 0; rg < 4; ++rg)
            acc[mt][g][rg] += sp[(rq * 4 + rg) * 17 + cl];
        }
      if (isXp) {
        float* xpd = sXP[(t + 1) & 1];
#pragma unroll
        for (int mt = 0; mt < 2; ++mt)
#pragma unroll
          for (int g = 0; g < 3; ++g)
#pragma unroll
            for (int rg = 0; rg < 4; ++rg)
              xpd[(mt * 16 + rq * 4 + rg) * 101 + g * 32 + chL] =
                  acc[mt][g][rg] + bh[g];
      }
    }
    // --- gh gates + publish + OWN drain + EARLY per-wave flag (no trailing barrier) ---
    if (!isXp && kh == 0) {
      const float* xps = sXP[t & 1];
      unsigned* rdst = ringAddr(l, t);
      unsigned xsv[2][4];
#pragma unroll
      for (int mt = 0; mt < 2; ++mt) {
        unsigned pk[4];
#pragma unroll
        for (int rg = 0; rg < 4; ++rg) {
          float h2;
          if (t >= 0) {
            int rloc = mt * 16 + rq * 4 + rg;
            float xr = xps[rloc * 101 + chL];
            float xz = xps[rloc * 101 + 32 + chL];
            float xn = xps[rloc * 101 + 64 + chL];
            float r = 1.f / (1.f + __expf(-(xr + acc[mt][0][rg] + bh[0])));
            float z = 1.f / (1.f + __expf(-(xz + acc[mt][1][rg] + bh[1])));
            float n = tanhf(xn + r * (acc[mt][2][rg] + bh[2]));
            h2 = (1.f - z) * n + z * mh[mt][rg];
            mh[mt][rg] = h2;
          } else {
            h2 = mh[mt][rg];   // t=-1: publish initial hidden state
          }
          pk[rg] = (unsigned)f2bf(h2);
        }
        xsv[mt][0] = pk[0]; xsv[mt][1] = pk[1]; xsv[mt][2] = pk[2]; xsv[mt][3] = pk[3];
#pragma unroll
        for (int rg = 0; rg < 4; ++rg) {
          unsigned prt = (unsigned)__shfl_xor((int)pk[rg], 1);
          if (!(cl & 1))
            __hip_atomic_store(
                &rdst[(bg * 32 + mt * 16 + rq * 4 + rg) * 256 + (ch >> 1)],
                pk[rg] | (prt << 16), __ATOMIC_RELAXED, __HIP_MEMORY_SCOPE_AGENT);
        }
      }
      asm volatile("s_waitcnt vmcnt(0)" ::: "memory");   // this wave's ring data at IC
      if (lane == 0)
        __hip_atomic_store(&myflags[(cg * 2 + nh) * 16], (unsigned)(t + 2),
                           __ATOMIC_RELAXED, __HIP_MEMORY_SCOPE_AGENT);
      // l=2 output stores after the flag: off the handshake critical path
      if (l == 2 && t >= 0) {
#pragma unroll
        for (int mt = 0; mt < 2; ++mt)
#pragma unroll
          for (int rg = 0; rg < 4; ++rg) {
            int rloc = mt * 16 + rq * 4 + rg;
            xout2[((long)(bg * 32 + rloc) * 512 + t) * 512 + ch] = (u16)xsv[mt][rg];
          }
      }
    }
    // no B3: next phase's B0 re-converges all waves; sXP/sPART races are
    // separated by B0/B1/B2 of the next phase.
  }
  if (!isXp && kh == 0) {
#pragma unroll
    for (int mt = 0; mt < 2; ++mt)
#pragma unroll
      for (int rg = 0; rg < 4; ++rg)
        hfin[(long)l * 65536 + (long)(bg * 32 + mt * 16 + rq * 4 + rg) * 512 + ch] =
            mh[mt][rg];
  }
}

extern "C" void kernel_launch(void* const* d_in, const int* in_sizes, int n_in,
                              void* d_out, int out_size, void* d_ws, size_t ws_size,
                              hipStream_t stream) {
  const int* padded    = (const int*)d_in[0];
  const float* enc     = (const float*)d_in[2];
  const float* hidden  = (const float*)d_in[3];
  const float* embedding = (const float*)d_in[4];
  const float* w_ih    = (const float*)d_in[5];
  const float* w_hh    = (const float*)d_in[6];
  const float* b_ih    = (const float*)d_in[7];
  const float* b_hh    = (const float*)d_in[8];
  const float* attn_w  = (const float*)d_in[9];
  const float* attn_b  = (const float*)d_in[10];
  const float* out_w   = (const float*)d_in[11];
  const float* out_b   = (const float*)d_in[12];

  if (ws_size < 280645632ULL) return;   // ws budget guard

  char* ws = (char*)d_ws;
  u16* W_IH   = (u16*)(ws + 0);               // 3*1536*512 bf16
  u16* W_HH   = (u16*)(ws + 4718592);
  u16* ATTN_W = (u16*)(ws + 9437184);         // 512*1024 bf16
  u16* OUT_W  = (u16*)(ws + 10485760);        // 100*512 bf16
  unsigned* FLAGS = (unsigned*)(ws + 10588160);   // 3*4*32 flags x 16 u32 pad = 24 KB
  unsigned* RINGM1 = (unsigned*)(ws + 10637312);  // 3 x 128KB h[-1] slots (1.5MB rsvd)
  u16* XA     = (u16*)(ws + 12210176);        // context bf16 (64 MB); ring2 during GRU
  u16* XB     = (u16*)(ws + 79319040);        // dec = layer-2 output, 64 MB
  u16* ENCT   = (u16*)(ws + 146427904);       // enc^T bf16, 64 MB
  u16* AMASK  = (u16*)(ws + 213536768);       // tanh-masked / softmax-bf16 alias, 64 MB
  u16* ATTN_BF = AMASK;

  float* out_logits = (float*)d_out;                 // 65536*100
  float* out_h      = out_logits + 6553600;          // 3*128*512
  float* out_attn   = out_h + 196608;                // 128*512*512; ring01 during GRU

  unsigned* RING01 = (unsigned*)out_attn;            // L0/L1 trajectories, 2*512*128KB
  unsigned* RING2  = (unsigned*)XA;                  // L2 trajectory, 512*128KB

  zero_flags<<<24, 256, 0, stream>>>(FLAGS, 6144);
  cvt_f32_bf16<<<512, 256, 0, stream>>>(w_ih, W_IH, 2359296 / 4);
  cvt_f32_bf16<<<512, 256, 0, stream>>>(w_hh, W_HH, 2359296 / 4);
  cvt_f32_bf16<<<256, 256, 0, stream>>>(attn_w, ATTN_W, 524288 / 4);
  cvt_f32_bf16<<<64, 256, 0, stream>>>(out_w, OUT_W, 51200 / 4);
  transpose_enc<<<dim3(8, 8, 128), 256, 0, stream>>>(enc, ENCT);

  gru_wave<<<192, 512, 0, stream>>>(
      padded, embedding, W_IH, W_HH, b_ih, b_hh, hidden,
      RING01, RING2, RINGM1, FLAGS, XB, out_h);

  // attention (scores GEMM converts f32 enc in staging; overwrites ring01 region)
  gemm_xwt<1, 1><<<dim3(4, 4, 128), 256, 0, stream>>>(
      XB, nullptr, (const u16*)enc, nullptr, out_attn, nullptr,
      512, 512, 512, 262144, 262144, 262144, 0.044194173824159216f, 512);
  softmax_rows<<<16384, 256, 0, stream>>>(out_attn, ATTN_BF);
  gemm_xwt<2, 0><<<dim3(4, 4, 128), 256, 0, stream>>>(
      ATTN_BF, nullptr, ENCT, nullptr, XA, nullptr,
      512, 512, 512, 262144, 262144, 262144, 1.f, 512);
  gemm_xwt<3, 0><<<dim3(4, 512, 1), 256, 0, stream>>>(
      XB, XA, ATTN_W, attn_b, AMASK, XB,
      512, 1024, 512, 0, 0, 0, 1.f, 512);
  gemm_xwt<4, 0><<<dim3(1, 512, 1), 256, 0, stream>>>(
      AMASK, nullptr, OUT_W, out_b, d_out, XB,
      100, 512, 512, 0, 0, 0, 1.f, 100);
}